// Round 7
// baseline (258.021 us; speedup 1.0000x reference)
//
#include <hip/hip_runtime.h>

// ---------------- quantum gate appliers (16-amp statevector in regs) ----------------
// wire w -> bit position (3 - w); bit 3 is MSB of the flat index (row-major reshape).

__device__ __forceinline__ void apply_rx(float* sr, float* si, int bit, float c, float s) {
    const int m = 1 << bit;
#pragma unroll
    for (int idx = 0; idx < 16; ++idx) {
        if (idx & m) continue;
        const int j = idx | m;
        float a0r = sr[idx], a0i = si[idx], a1r = sr[j], a1i = si[j];
        // U = [[c, -i s], [-i s, c]]
        sr[idx] = c * a0r + s * a1i;
        si[idx] = c * a0i - s * a1r;
        sr[j]   = c * a1r + s * a0i;
        si[j]   = c * a1i - s * a0r;
    }
}

__device__ __forceinline__ void apply_ry(float* sr, float* si, int bit, float c, float s) {
    const int m = 1 << bit;
#pragma unroll
    for (int idx = 0; idx < 16; ++idx) {
        if (idx & m) continue;
        const int j = idx | m;
        float a0r = sr[idx], a0i = si[idx], a1r = sr[j], a1i = si[j];
        // U = [[c, -s], [s, c]]
        sr[idx] = c * a0r - s * a1r;
        si[idx] = c * a0i - s * a1i;
        sr[j]   = s * a0r + c * a1r;
        si[j]   = s * a0i + c * a1i;
    }
}

__device__ __forceinline__ void apply_rz(float* sr, float* si, int bit, float c, float s) {
    const int m = 1 << bit;
#pragma unroll
    for (int idx = 0; idx < 16; ++idx) {
        if (idx & m) continue;
        const int j = idx | m;
        float a0r = sr[idx], a0i = si[idx], a1r = sr[j], a1i = si[j];
        // diag(e^{-i t/2}, e^{+i t/2}) ; c = cos(t/2), s = sin(t/2)
        sr[idx] = c * a0r + s * a0i;
        si[idx] = c * a0i - s * a0r;
        sr[j]   = c * a1r - s * a1i;
        si[j]   = c * a1i + s * a1r;
    }
}

__device__ __forceinline__ void apply_cnot(float* sr, float* si, int cw, int tw) {
    const int cb = 3 - cw, tb = 3 - tw;
#pragma unroll
    for (int idx = 0; idx < 16; ++idx) {
        if (((idx >> cb) & 1) && !((idx >> tb) & 1)) {
            const int j = idx | (1 << tb);
            float tr = sr[idx]; sr[idx] = sr[j]; sr[j] = tr;
            float ti = si[idx]; si[idx] = si[j]; si[j] = ti;
        }
    }
}

// ---------------- kernel 1: fused pool + angles + circuit + BN partials ----------------
// R1's verified pool structure verbatim (8 samples/block, 256 threads, ~19 KB LDS,
// 8 blocks/CU). After pooling, wave 0 (t<32: 8 samples x 4 lanes) computes angles
// (R1 math), gathers the 4 angles per sample via absolute-lane shfl (static regs),
// runs the circuit 4x-redundantly (R1/R3-verified math), stores z coalesced, and
// reduces BN partials within wave 0 (width-32, x0.25 for redundancy).
// Circuit adds ~1 wave x ~4k cyc per block -> ~13 us/CU total, overlapped under the
// ~24 us/CU HBM stream of the 8 resident blocks.

__global__ __launch_bounds__(256) void fused_pool_circuit(
    const float4* __restrict__ x,           // fp32 x viewed as float4 (144 per sample)
    const float* __restrict__ enc_w,        // [4,16]
    const float* __restrict__ enc_b,        // [4]
    const float* __restrict__ var_params,   // [2,4,3] = 24
    float* __restrict__ out_z,              // [B*4] fp32 z (= d_out, finalized by bn)
    float* __restrict__ partials)           // [gridDim.x * 8]
{
    __shared__ float4 xbuf[8 * 144];        // 18432 B, exact copy of 8 samples
    __shared__ float pooled[8][17];         // padded
    __shared__ float gc[24], gs[24];        // gate tables

    const int t = threadIdx.x;
    const int blk = blockIdx.x;

    // ---- stage 8 samples * 144 float4 = 1152 float4, coalesced (R1 verbatim) ----
    const float4* src = x + (size_t)blk * 1152;
    float4 v0 = src[t];
    float4 v1 = src[t + 256];
    float4 v2 = src[t + 512];
    float4 v3 = src[t + 768];
    float4 v4;
    if (t < 128) v4 = src[1024 + t];

    // gate tables while the stage loads are in flight (R1 circuit-kernel pattern)
    if (t < 24) {
        float th = 0.5f * var_params[t];
        float s, c;
        __sincosf(th, &s, &c);
        gc[t] = c; gs[t] = s;
    }

    xbuf[t] = v0;
    xbuf[t + 256] = v1;
    xbuf[t + 512] = v2;
    xbuf[t + 768] = v3;
    if (t < 128) xbuf[1024 + t] = v4;
    __syncthreads();

    // ---- pooling: 256 threads = 8 samples x 16 cells x 2 halves (R1 verbatim) ----
    {
        const int s = t >> 5;               // sample 0..7
        const int q = t & 31;
        const int cell = q & 15;            // pool cell 0..15 (pr*4+pc)
        const int half = q >> 4;            // 0: rows 0-2, 1: rows 3-5
        const int pr = cell >> 2, pc = cell & 3;
        const float* sb = reinterpret_cast<const float*>(xbuf) + s * 576;
        const int base = pr * 144 + pc * 6 + half * 72;
        float acc = 0.0f;
        // row order rotated by pr to break pr-parity bank aliasing
#pragma unroll
        for (int r0 = 0; r0 < 3; ++r0) {
            int r = r0 + (pr & 3);
            if (r >= 3) r -= 3;
            const int rowbase = base + r * 24;
#pragma unroll
            for (int c = 0; c < 6; ++c)
                acc += sb[rowbase + c];
        }
        acc += __shfl_xor(acc, 16, 64);     // combine the two halves (same wave)
        if (half == 0)
            pooled[s][cell] = acc * (1.0f / 36.0f);
    }
    __syncthreads();

    if (t >= 32) return;                    // waves 1-3 done; wave 0 lanes 32-63 masked

    // ---- angles: lane t -> (sample s = t>>2, angle i = t&3), R1 math verbatim ----
    const int s = t >> 2, i = t & 3;
    float a = enc_b[i];
#pragma unroll
    for (int k = 0; k < 16; ++k)
        a += enc_w[i * 16 + k] * pooled[s][k];

    // gather all 4 angles of this sample from the 4-lane group (static dests)
    const int lane0 = t & ~3;
    float av[4];
    av[0] = __shfl(a, lane0 + 0, 64);
    av[1] = __shfl(a, lane0 + 1, 64);
    av[2] = __shfl(a, lane0 + 2, 64);
    av[3] = __shfl(a, lane0 + 3, 64);

    // ---- statevector simulation (R1 circuit-kernel body, gc/gs from LDS) ----
    float sr[16], si[16];
#pragma unroll
    for (int idx = 0; idx < 16; ++idx) { sr[idx] = 0.0f; si[idx] = 0.0f; }
    sr[0] = 1.0f;

#pragma unroll
    for (int w = 0; w < 4; ++w) {
        float sn, cs;
        __sincosf(0.5f * av[w], &sn, &cs);
        apply_rx(sr, si, 3 - w, cs, sn);
    }

#pragma unroll
    for (int d = 0; d < 2; ++d) {
#pragma unroll
        for (int w = 0; w < 4; ++w) {
            const int base = d * 12 + w * 3;
            apply_rx(sr, si, 3 - w, gc[base + 0], gs[base + 0]);
            apply_ry(sr, si, 3 - w, gc[base + 1], gs[base + 1]);
            apply_rz(sr, si, 3 - w, gc[base + 2], gs[base + 2]);
        }
        apply_cnot(sr, si, 0, 1);
        apply_cnot(sr, si, 1, 2);
        apply_cnot(sr, si, 2, 3);
        apply_cnot(sr, si, 3, 0);
    }

    float pr16[16];
#pragma unroll
    for (int idx = 0; idx < 16; ++idx) pr16[idx] = sr[idx] * sr[idx] + si[idx] * si[idx];

    float z[4];
#pragma unroll
    for (int w = 0; w < 4; ++w) {
        const int bit = 3 - w;
        float acc = 0.0f;
#pragma unroll
        for (int idx = 0; idx < 16; ++idx)
            acc += ((idx >> bit) & 1) ? -pr16[idx] : pr16[idx];
        z[w] = acc;
    }

    // z component q of sample s, element index (blk*8+s)*4+q = blk*32 + t -> coalesced
    out_z[blk * 32 + t] = z[i];

    // ---- BN partials within wave-0's 32 active lanes (4x redundancy -> x0.25) ----
    float vals[8] = {z[0], z[1], z[2], z[3],
                     z[0] * z[0], z[1] * z[1], z[2] * z[2], z[3] * z[3]};
#pragma unroll
    for (int j = 0; j < 8; ++j) {
        float v = vals[j];
#pragma unroll
        for (int off = 16; off >= 1; off >>= 1)
            v += __shfl_down(v, off, 32);   // width 32: never touches inactive lanes
        if (t == 0) partials[blk * 8 + j] = 0.25f * v;
    }
}

// ---------------- kernel 2: batchnorm finalize; fp32 z -> fp32 out (in place) ----------------
// Verbatim from the harness-verified R1 kernel (nPartialRows now 8192).
__global__ __launch_bounds__(256) void bn_kernel(
    float4* __restrict__ io,                // [B] fp32 z quads -> out quads (= d_out)
    const float* __restrict__ partials,     // [nPartialRows * 8]
    const float* __restrict__ gamma,
    const float* __restrict__ beta,
    int nPartialRows, int B)
{
    __shared__ float stats[8];
    const int t = threadIdx.x;

    if (t < 64) {
        float part[8];
#pragma unroll
        for (int j = 0; j < 8; ++j) part[j] = 0.0f;
        for (int r = t; r < nPartialRows; r += 64) {
            const float* row = partials + r * 8;
#pragma unroll
            for (int j = 0; j < 8; ++j) part[j] += row[j];
        }
#pragma unroll
        for (int j = 0; j < 8; ++j) {
            float v = part[j];
#pragma unroll
            for (int off = 32; off >= 1; off >>= 1)
                v += __shfl_down(v, off, 64);
            if (t == 0) stats[j] = v;
        }
    }
    __syncthreads();

    const int b = blockIdx.x * 256 + t;
    const float invB = 1.0f / (float)B;
    const float4 z4 = io[b];
    const float zz[4] = {z4.x, z4.y, z4.z, z4.w};

    float res[4];
#pragma unroll
    for (int i = 0; i < 4; ++i) {
        const float mean = stats[i] * invB;
        float var = stats[4 + i] * invB - mean * mean;
        var = fmaxf(var, 0.0f);
        const float scale = gamma[i] * rsqrtf(var + 1e-5f);
        res[i] = (zz[i] - mean) * scale + beta[i];
    }
    io[b] = make_float4(res[0], res[1], res[2], res[3]);
}

// ---------------- launch ----------------
extern "C" void kernel_launch(void* const* d_in, const int* in_sizes, int n_in,
                              void* d_out, int out_size, void* d_ws, size_t ws_size,
                              hipStream_t stream) {
    const float4* x = (const float4*)d_in[0];
    const float* enc_w = (const float*)d_in[1];
    const float* enc_b = (const float*)d_in[2];
    const float* var_params = (const float*)d_in[3];
    const float* gamma = (const float*)d_in[4];
    const float* beta = (const float*)d_in[5];

    const int B = in_sizes[0] / 576;            // 65536
    float* io = (float*)d_out;                  // B*4 floats (z -> out, in place)
    float* partials = (float*)d_ws;             // 8192*8 floats = 256 KB

    const int nBlocks = B / 8;                  // 8192

    fused_pool_circuit<<<nBlocks, 256, 0, stream>>>(x, enc_w, enc_b, var_params,
                                                    io, partials);
    bn_kernel<<<B / 256, 256, 0, stream>>>((float4*)io, partials, gamma, beta,
                                           nBlocks, B);
}

// Round 8
// 234.536 us; speedup vs baseline: 1.1001x; 1.1001x over previous
//
#include <hip/hip_runtime.h>

// ---------------- quantum gate appliers (16-amp statevector in regs) ----------------
// wire w -> bit position (3 - w); bit 3 is MSB of the flat index (row-major reshape).

__device__ __forceinline__ void apply_rx(float* sr, float* si, int bit, float c, float s) {
    const int m = 1 << bit;
#pragma unroll
    for (int idx = 0; idx < 16; ++idx) {
        if (idx & m) continue;
        const int j = idx | m;
        float a0r = sr[idx], a0i = si[idx], a1r = sr[j], a1i = si[j];
        // U = [[c, -i s], [-i s, c]]
        sr[idx] = c * a0r + s * a1i;
        si[idx] = c * a0i - s * a1r;
        sr[j]   = c * a1r + s * a0i;
        si[j]   = c * a1i - s * a0r;
    }
}

__device__ __forceinline__ void apply_ry(float* sr, float* si, int bit, float c, float s) {
    const int m = 1 << bit;
#pragma unroll
    for (int idx = 0; idx < 16; ++idx) {
        if (idx & m) continue;
        const int j = idx | m;
        float a0r = sr[idx], a0i = si[idx], a1r = sr[j], a1i = si[j];
        // U = [[c, -s], [s, c]]
        sr[idx] = c * a0r - s * a1r;
        si[idx] = c * a0i - s * a1i;
        sr[j]   = s * a0r + c * a1r;
        si[j]   = s * a0i + c * a1i;
    }
}

__device__ __forceinline__ void apply_rz(float* sr, float* si, int bit, float c, float s) {
    const int m = 1 << bit;
#pragma unroll
    for (int idx = 0; idx < 16; ++idx) {
        if (idx & m) continue;
        const int j = idx | m;
        float a0r = sr[idx], a0i = si[idx], a1r = sr[j], a1i = si[j];
        // diag(e^{-i t/2}, e^{+i t/2}) ; c = cos(t/2), s = sin(t/2)
        sr[idx] = c * a0r + s * a0i;
        si[idx] = c * a0i - s * a0r;
        sr[j]   = c * a1r - s * a1i;
        si[j]   = c * a1i + s * a1r;
    }
}

__device__ __forceinline__ void apply_cnot(float* sr, float* si, int cw, int tw) {
    const int cb = 3 - cw, tb = 3 - tw;
#pragma unroll
    for (int idx = 0; idx < 16; ++idx) {
        if (((idx >> cb) & 1) && !((idx >> tb) & 1)) {
            const int j = idx | (1 << tb);
            float tr = sr[idx]; sr[idx] = sr[j]; sr[j] = tr;
            float ti = si[idx]; si[idx] = si[j]; si[j] = ti;
        }
    }
}

// ---------------- kernel 1: LDS-free barrier-free pool + angles + circuit + partials ----------------
// 4 lanes per sample. At step j, lane q loads float4[4j+q] of its sample: adjacent
// lanes -> adjacent 16B, so each wave instruction covers 16 fully-consumed 64B lines
// (same txn profile as the verified R1 staging). Lane-side addresses are one base +
// compile-time immediate offsets -> all 36 loads issue back-to-back, never drained
// by any barrier. Pooling: element (j,c) has pool-row j/9 (compile-time) and pool-col
// pcs[j%3][c] (precomputed per-lane) -> 4-way masked adds, all array indices static.
// Then 4-lane shfl_xor combine -> full pooled[16] per lane -> angles -> circuit
// (R2/R5-verified math, 4x redundant) -> coalesced z store + R5-verified partials.

__global__ __launch_bounds__(256) void fused_stream(
    const float4* __restrict__ x,           // fp32 x viewed as float4 (144 per sample)
    const float* __restrict__ enc_w,        // [4,16]
    const float* __restrict__ enc_b,        // [4]
    const float* __restrict__ var_params,   // [2,4,3] = 24
    float* __restrict__ out_z,              // [B*4] fp32 z (= d_out, finalized by bn)
    float* __restrict__ partials)           // [gridDim.x * 8]
{
    __shared__ float red[4 * 8];

    const int t = threadIdx.x;
    const int q = t & 3;                    // lane within 4-lane sample group
    const int s = blockIdx.x * 64 + (t >> 2);   // sample index (w*16+g folded in t>>2)

    // per-lane base: fold q into the pointer -> loads are base + 64*j immediates
    const float4* xsq = x + (size_t)s * 144 + q;

    // pool-col table: element (j,c) of lane q has col = (16*(j%3))%24 + 4q + c (mod 24)
    // K0 = {0,16,8} for j%3 = {0,1,2}; after reducing K0+4q mod 24, +c never wraps.
    int cb0 = 4 * q;                        // K0 = 0
    int cb1 = 16 + 4 * q; if (cb1 >= 24) cb1 -= 24;  // K0 = 16
    int cb2 = 8 + 4 * q;                    // K0 = 8 (max 20, no wrap)
    int pcs[3][4];
#pragma unroll
    for (int c = 0; c < 4; ++c) {
        pcs[0][c] = (cb0 + c) / 6;
        pcs[1][c] = (cb1 + c) / 6;
        pcs[2][c] = (cb2 + c) / 6;
    }

    // ---- stream 36 float4 + masked-add pooling (16 cells, static indices) ----
    float pacc[16];
#pragma unroll
    for (int i = 0; i < 16; ++i) pacc[i] = 0.0f;

#pragma unroll
    for (int j = 0; j < 36; ++j) {
        const float4 v = xsq[4 * j];        // = sample float4[4j+q]
        const int r4 = (j / 9) * 4;         // compile-time pool row * 4
        const int m = j % 3;                // compile-time col-class
        const float e[4] = {v.x, v.y, v.z, v.w};
#pragma unroll
        for (int c = 0; c < 4; ++c) {
#pragma unroll
            for (int p = 0; p < 4; ++p)
                pacc[r4 + p] += (pcs[m][c] == p) ? e[c] : 0.0f;
        }
    }

    // ---- combine across the 4-lane group; every lane gets full pooled[16] ----
    float pooled[16];
#pragma unroll
    for (int k = 0; k < 16; ++k) {
        float p = pacc[k];
        p += __shfl_xor(p, 1, 64);
        p += __shfl_xor(p, 2, 64);
        pooled[k] = p * (1.0f / 36.0f);
    }

    // ---- angles locally (enc_w/enc_b wave-uniform -> s_loads) ----
    float av[4];
#pragma unroll
    for (int i = 0; i < 4; ++i) {
        float a = enc_b[i];
#pragma unroll
        for (int k = 0; k < 16; ++k)
            a += enc_w[i * 16 + k] * pooled[k];
        av[i] = a;
    }

    // ---- gate tables (uniform params; R5-verified pattern) ----
    float gc[24], gs[24];
#pragma unroll
    for (int i = 0; i < 24; ++i) {
        float sn, cs;
        __sincosf(0.5f * var_params[i], &sn, &cs);
        gc[i] = cs; gs[i] = sn;
    }

    // ---- statevector simulation, all in registers (R2/R5-verified) ----
    float sr[16], si[16];
#pragma unroll
    for (int i = 0; i < 16; ++i) { sr[i] = 0.0f; si[i] = 0.0f; }
    sr[0] = 1.0f;

#pragma unroll
    for (int w = 0; w < 4; ++w) {
        float sn, cs;
        __sincosf(0.5f * av[w], &sn, &cs);
        apply_rx(sr, si, 3 - w, cs, sn);
    }

#pragma unroll
    for (int d = 0; d < 2; ++d) {
#pragma unroll
        for (int w = 0; w < 4; ++w) {
            const int base = d * 12 + w * 3;
            apply_rx(sr, si, 3 - w, gc[base + 0], gs[base + 0]);
            apply_ry(sr, si, 3 - w, gc[base + 1], gs[base + 1]);
            apply_rz(sr, si, 3 - w, gc[base + 2], gs[base + 2]);
        }
        apply_cnot(sr, si, 0, 1);
        apply_cnot(sr, si, 1, 2);
        apply_cnot(sr, si, 2, 3);
        apply_cnot(sr, si, 3, 0);
    }

    float pr16[16];
#pragma unroll
    for (int i = 0; i < 16; ++i) pr16[i] = sr[i] * sr[i] + si[i] * si[i];

    float z[4];
#pragma unroll
    for (int w = 0; w < 4; ++w) {
        const int bit = 3 - w;
        float acc = 0.0f;
#pragma unroll
        for (int i = 0; i < 16; ++i)
            acc += ((i >> bit) & 1) ? -pr16[i] : pr16[i];
        z[w] = acc;
    }

    // z component q of sample s: element s*4+q = blk*256+t -> fully coalesced
    out_z[blockIdx.x * 256 + t] = z[q];

    // ---- block partials: sum(z), sum(z^2); 4x redundancy -> x0.25 (R5-verified) ----
    float vals[8] = {z[0], z[1], z[2], z[3],
                     z[0] * z[0], z[1] * z[1], z[2] * z[2], z[3] * z[3]};
#pragma unroll
    for (int j = 0; j < 8; ++j) {
        float v = vals[j];
#pragma unroll
        for (int off = 32; off >= 1; off >>= 1)
            v += __shfl_down(v, off, 64);
        if ((t & 63) == 0) red[(t >> 6) * 8 + j] = v;
    }
    __syncthreads();
    if (t < 8)
        partials[blockIdx.x * 8 + t] =
            0.25f * (red[t] + red[8 + t] + red[16 + t] + red[24 + t]);
}

// ---------------- kernel 2: batchnorm finalize; fp32 z -> fp32 out (in place) ----------------
// Verbatim from the harness-verified R1 kernel (nPartialRows = 1024).
__global__ __launch_bounds__(256) void bn_kernel(
    float4* __restrict__ io,                // [B] fp32 z quads -> out quads (= d_out)
    const float* __restrict__ partials,     // [nPartialRows * 8]
    const float* __restrict__ gamma,
    const float* __restrict__ beta,
    int nPartialRows, int B)
{
    __shared__ float stats[8];
    const int t = threadIdx.x;

    if (t < 64) {
        float part[8];
#pragma unroll
        for (int j = 0; j < 8; ++j) part[j] = 0.0f;
        for (int r = t; r < nPartialRows; r += 64) {
            const float* row = partials + r * 8;
#pragma unroll
            for (int j = 0; j < 8; ++j) part[j] += row[j];
        }
#pragma unroll
        for (int j = 0; j < 8; ++j) {
            float v = part[j];
#pragma unroll
            for (int off = 32; off >= 1; off >>= 1)
                v += __shfl_down(v, off, 64);
            if (t == 0) stats[j] = v;
        }
    }
    __syncthreads();

    const int b = blockIdx.x * 256 + t;
    const float invB = 1.0f / (float)B;
    const float4 z4 = io[b];
    const float zz[4] = {z4.x, z4.y, z4.z, z4.w};

    float res[4];
#pragma unroll
    for (int i = 0; i < 4; ++i) {
        const float mean = stats[i] * invB;
        float var = stats[4 + i] * invB - mean * mean;
        var = fmaxf(var, 0.0f);
        const float scale = gamma[i] * rsqrtf(var + 1e-5f);
        res[i] = (zz[i] - mean) * scale + beta[i];
    }
    io[b] = make_float4(res[0], res[1], res[2], res[3]);
}

// ---------------- launch ----------------
extern "C" void kernel_launch(void* const* d_in, const int* in_sizes, int n_in,
                              void* d_out, int out_size, void* d_ws, size_t ws_size,
                              hipStream_t stream) {
    const float4* x = (const float4*)d_in[0];
    const float* enc_w = (const float*)d_in[1];
    const float* enc_b = (const float*)d_in[2];
    const float* var_params = (const float*)d_in[3];
    const float* gamma = (const float*)d_in[4];
    const float* beta = (const float*)d_in[5];

    const int B = in_sizes[0] / 576;            // 65536
    float* out = (float*)d_out;                 // B*4 floats (z -> out, in place)
    float* partials = (float*)d_ws;             // 1024*8 floats = 32 KB

    const int nBlocks = B / 64;                 // 1024

    fused_stream<<<nBlocks, 256, 0, stream>>>(x, enc_w, enc_b, var_params,
                                              out, partials);
    bn_kernel<<<B / 256, 256, 0, stream>>>((float4*)out, partials, gamma, beta,
                                           nBlocks, B);
}